// Round 6
// baseline (947.913 us; speedup 1.0000x reference)
//
#include <hip/hip_runtime.h>

typedef __bf16 bf16_t;
typedef bf16_t bf16x8 __attribute__((ext_vector_type(8)));
typedef float  floatx4 __attribute__((ext_vector_type(4)));
typedef unsigned short u16;
typedef unsigned int   u32;
typedef unsigned long long u64;

#define DEV __device__ __forceinline__

static constexpr int B_  = 256;
static constexpr int T_  = 64;
static constexpr int H_  = 512;
static constexpr int G_  = 2048;   // 4*H
static constexpr int INS = 500;
static constexpr int NDP = 16640;  // padded OUT_DIM
static constexpr int NDR = 16532;  // real OUT_DIM

DEV u16 f2bf(float f) {
  unsigned u = __builtin_bit_cast(unsigned, f);
  u += 0x7FFFu + ((u >> 16) & 1u);
  return (u16)(u >> 16);
}
DEV float bf2f(u16 h) {
  unsigned u = ((unsigned)h) << 16;
  return __builtin_bit_cast(float, u);
}
DEV float sigm(float x)  { return 1.f / (1.f + __expf(-x)); }
DEV float tanh_(float x) { return 1.f - 2.f / (__expf(2.f * x) + 1.f); }

DEV void gload16(const u16* g, u16* l) {
  __builtin_amdgcn_global_load_lds(
      (const __attribute__((address_space(1))) void*)g,
      (__attribute__((address_space(3))) void*)l, 16, 0, 0);
}

// all-wave poll: lanes 0..31 check flags (skipping own block's), lanes 32+ idle-true
DEV void pollflag(unsigned* f, unsigned tgt, int lane, int self) {
  for (;;) {
    unsigned v = tgt;
    if (lane < 32 && lane != self)
      v = __hip_atomic_load(f + lane, __ATOMIC_RELAXED, __HIP_MEMORY_SCOPE_AGENT);
    if (__all(v >= tgt)) break;
    __builtin_amdgcn_s_sleep(1);
  }
}

// ---------------------------------------------------------------- prep kernels
__global__ void prep_weights_kernel(
    const float* __restrict__ w_ih0, const float* __restrict__ w_hh0,
    const float* __restrict__ b_ih0, const float* __restrict__ b_hh0,
    const float* __restrict__ w_ih1, const float* __restrict__ w_hh1,
    const float* __restrict__ b_ih1, const float* __restrict__ b_hh1,
    const float* __restrict__ fc_w,  const float* __restrict__ fc_b,
    u16* __restrict__ wih0b, u16* __restrict__ whh0b,
    u16* __restrict__ w1b,   u16* __restrict__ fcwb,
    float* __restrict__ bias0p, float* __restrict__ bias1p,
    float* __restrict__ fcbp)
{
  const int gsz = gridDim.x * blockDim.x;
  const int g0  = blockIdx.x * blockDim.x + threadIdx.x;
  // permuted gate order: p = (j>>4)*64 + (j&15)*4 + g  (j = hidden, g = i/f/g/o)
  for (int i = g0; i < 2048 * 512; i += gsz) {
    int pp = i >> 9, k = i & 511;
    int s = pp >> 6, rr = pp & 63, jj = rr >> 2, g = rr & 3;
    int srow = g * 512 + s * 16 + jj;
    wih0b[i] = f2bf(k < INS ? w_ih0[(size_t)srow * INS + k] : 0.f);
    whh0b[i] = f2bf(w_hh0[(size_t)srow * 512 + k]);
  }
  for (int i = g0; i < 2048 * 1024; i += gsz) {
    int pp = i >> 10, k = i & 1023;
    int s = pp >> 6, rr = pp & 63, jj = rr >> 2, g = rr & 3;
    int srow = g * 512 + s * 16 + jj;
    float v = (k < 512) ? w_ih1[(size_t)srow * 512 + k]
                        : w_hh1[(size_t)srow * 512 + (k - 512)];
    w1b[i] = f2bf(v);
  }
  for (int i = g0; i < NDP * 512; i += gsz) {
    int n = i >> 9, k = i & 511;
    fcwb[i] = f2bf(n < NDR ? fc_w[(size_t)n * 512 + k] : 0.f);
  }
  for (int i = g0; i < 2048; i += gsz) {
    int s = i >> 6, rr = i & 63, jj = rr >> 2, g = rr & 3;
    int srow = g * 512 + s * 16 + jj;
    bias0p[i] = b_ih0[srow] + b_hh0[srow];
    bias1p[i] = b_ih1[srow] + b_hh1[srow];
  }
  for (int i = g0; i < NDP; i += gsz) fcbp[i] = (i < NDR) ? fc_b[i] : 0.f;
}

__global__ void prep_x_kernel(const float* __restrict__ x, u16* __restrict__ xb) {
  const int gsz = gridDim.x * blockDim.x;
  for (int i = blockIdx.x * blockDim.x + threadIdx.x; i < T_ * B_ * 512; i += gsz) {
    int k = i & 511;
    int b = (i >> 9) & 255;
    int t = i >> 17;
    float v = (k < INS) ? x[((size_t)b * T_ + t) * INS + k] : 0.f;
    xb[i] = f2bf(v);
  }
}

__global__ void prep_sigma_kernel(const float* __restrict__ raw,
                                  u16* __restrict__ Gb, u16* __restrict__ Ldb,
                                  float* __restrict__ idio)
{
  const int gsz = gridDim.x * blockDim.x;
  const int g0  = blockIdx.x * blockDim.x + threadIdx.x;
  for (int i = g0; i < 256 * 512 * 32; i += gsz) {
    int b = i >> 14, rr = i & 16383, n = rr >> 5, f = rr & 31;
    const float* rb = raw + (size_t)b * NDP;
    float ld = (n < 500) ? rb[n * 32 + f] : 0.f;
    float fv = __expf(rb[16000 + f]);
    Ldb[i] = f2bf(ld);
    Gb[i]  = f2bf(ld * fv);
  }
  for (int i = g0; i < 256 * 512; i += gsz) {
    int b = i >> 9, a = i & 511;
    if (a < 500) idio[(size_t)b * 500 + a] = __expf(raw[(size_t)b * NDP + 16032 + a]);
  }
}

// ---------------------------------------------------------------- GEMM: C[M][N] = A[M][K] @ Bw[N][K]^T + bias
template <int OUT_BF16>
__global__ __launch_bounds__(256) void gemm_bt(
    const u16* __restrict__ A, const u16* __restrict__ Bw,
    const float* __restrict__ bias, void* __restrict__ C,
    int M, int N, int K)
{
  __shared__ alignas(16) u16 As[128 * 32];
  __shared__ alignas(16) u16 Bs[128 * 32];
  const int tid = threadIdx.x;
  const int wave = tid >> 6, lane = tid & 63;
  const int m0 = blockIdx.y * 128, n0 = blockIdx.x * 128;
  const int wr = wave >> 1, wc = wave & 1;

  const int sl0 = wave * 64 + lane;
  const int sl1 = 256 + wave * 64 + lane;
  const int r0s = sl0 >> 2, k0s = (sl0 & 3) ^ (r0s & 3);
  const int r1s = sl1 >> 2, k1s = (sl1 & 3) ^ (r1s & 3);
  const u16* srcA0 = A  + (size_t)(m0 + r0s) * K + k0s * 8;
  const u16* srcA1 = A  + (size_t)(m0 + r1s) * K + k1s * 8;
  const u16* srcB0 = Bw + (size_t)(n0 + r0s) * K + k0s * 8;
  const u16* srcB1 = Bw + (size_t)(n0 + r1s) * K + k1s * 8;
  u16* ldsA0 = As + (size_t)(wave * 64) * 8;
  u16* ldsA1 = As + (size_t)(256 + wave * 64) * 8;
  u16* ldsB0 = Bs + (size_t)(wave * 64) * 8;
  u16* ldsB1 = Bs + (size_t)(256 + wave * 64) * 8;

  floatx4 zero = {0.f, 0.f, 0.f, 0.f};
  floatx4 acc[4][4];
#pragma unroll
  for (int i = 0; i < 4; i++)
#pragma unroll
    for (int j = 0; j < 4; j++) acc[i][j] = zero;

  for (int kc = 0; kc < K; kc += 32) {
    __syncthreads();
    gload16(srcA0 + kc, ldsA0);
    gload16(srcA1 + kc, ldsA1);
    gload16(srcB0 + kc, ldsB0);
    gload16(srcB1 + kc, ldsB1);
    __syncthreads();

    const int kg = lane >> 4;
    bf16x8 af[4], bfr[4];
#pragma unroll
    for (int i = 0; i < 4; i++) {
      int rowa = wr * 64 + i * 16 + (lane & 15);
      af[i] = *(const bf16x8*)(As + rowa * 32 + ((kg ^ (rowa & 3)) << 3));
      int rowb = wc * 64 + i * 16 + (lane & 15);
      bfr[i] = *(const bf16x8*)(Bs + rowb * 32 + ((kg ^ (rowb & 3)) << 3));
    }
#pragma unroll
    for (int i = 0; i < 4; i++)
#pragma unroll
      for (int j = 0; j < 4; j++)
        acc[i][j] = __builtin_amdgcn_mfma_f32_16x16x32_bf16(af[i], bfr[j], acc[i][j], 0, 0, 0);
  }

  const int r0 = (lane >> 4) * 4, cl = lane & 15;
#pragma unroll
  for (int j = 0; j < 4; j++) {
    int col = n0 + wc * 64 + j * 16 + cl;
    float bv = bias[col];
#pragma unroll
    for (int i = 0; i < 4; i++) {
      int row = m0 + wr * 64 + i * 16 + r0;
#pragma unroll
      for (int r = 0; r < 4; r++) {
        float v = acc[i][j][r] + bv;
        if (OUT_BF16) ((u16*)C)[(size_t)(row + r) * N + col] = f2bf(v);
        else          ((float*)C)[(size_t)(row + r) * N + col] = v;
      }
    }
  }
}

// ---------------------------------------------------------------- Fused 2-layer LSTM (round 6)
// 256 blocks x 512 threads (1/CU). bm = blockIdx>>5 (8 batch groups of 32),
// bn = blockIdx&31 (32 gate slices of 64 rows). Waves (rw 0..3, kh 0..1).
// Serial-work-minimized structure (round-5 post-mortem: polls are pre-satisfied;
// the iteration is serial-work-bound, not wait-bound):
//  * 3 __syncthreads per iteration (vs 8 in round 5).
//  * Role rebalance for LDS A-read REUSE (A-reads were ~384 KB/block/iter):
//      kh0: wfx = W_hh0 full-K (L0 complete in-wave) + wfy = w_ih1 chunks 0-7
//      kh1: wfx = w_hh1 full (pB)                    + wfy = w_ih1 chunks 8-15
//    -> 96 VGPR weights + 48 MFMAs per wave, h0 chunk loads shared by L0+pA.
//  * L0 gates complete inside kh0 waves -> in-wave scratch transpose,
//    no block-wide L0 gate combine / barrier.
//  * h1(t-2) stage loads issued BEFORE the MFMA block (RT hides under C);
//    h0(t) re-staged at iteration end (RT hides under L1 elementwise).
//  * Polls skip the self-flag lane.
// Flag/slot protocol identical to round 5 (proven): flag0=t+1 after h0(t) drain
// (sync2 drains); flag1=t after h1(t-1) drain (sync3 drains). Overwrite-safety
// induction as round 5; the t=0/1 hp1-slot0 case is covered by the flag0 chain.
__global__ __launch_bounds__(512, 2) void lstm_fused_kernel(
    const u16* __restrict__ xg,     // [64][256][2048] bf16, permuted gate order
    const u16* __restrict__ whh0,   // [2048][512]  bf16, permuted rows
    const u16* __restrict__ w1,     // [2048][1024] bf16, permuted rows, cols [w_ih1 | w_hh1]
    const float* __restrict__ bias1p,
    u16* __restrict__ hp0,          // [2][256][512] ping-pong h0
    u16* __restrict__ hp1,          // [2][256][512] ping-pong h1
    u16* __restrict__ hfin,         // [256][512] final h1(63)
    unsigned* __restrict__ bars)    // [8][64]: [bm][0..31]=flag0, [bm][32..63]=flag1
{
  const int tid  = threadIdx.x;
  const int wv   = tid >> 6, lane = tid & 63;
  const int rw   = wv >> 1,  kh   = wv & 1;
  const int bl   = lane & 15, qd  = lane >> 4;
  const int bm   = blockIdx.x >> 5;
  const int bn   = blockIdx.x & 31;
  const int bbase = bm << 5;        // 32 batches
  const int pbase = bn << 6;        // 64 gate rows

  __shared__ alignas(16) u16 h_lds[2 * 32 * 512];   // 64 KB: [0]=h0(t-1), [1]=h1(t-2)
  __shared__ alignas(16) float gates1[2 * 32 * 68]; // L1 partial gates (kh combine)
  __shared__ alignas(16) float scr[4 * 32 * 20];    // kh0 per-wave transpose scratch

  // weights: 24 bf16x8 fragments per wave (96 VGPR)
  bf16x8 wfx[16], wfy[8];
  {
    const int row = pbase + rw * 16 + bl;
    if (kh == 0) {
      const u16* wp = whh0 + (size_t)row * 512 + qd * 8;
#pragma unroll
      for (int kc = 0; kc < 16; kc++) wfx[kc] = *(const bf16x8*)(wp + kc * 32);
      const u16* wq = w1 + (size_t)row * 1024 + qd * 8;
#pragma unroll
      for (int kc = 0; kc < 8; kc++)  wfy[kc] = *(const bf16x8*)(wq + kc * 32);
    } else {
      const u16* wq = w1 + (size_t)row * 1024 + qd * 8;
#pragma unroll
      for (int kc = 0; kc < 16; kc++) wfx[kc] = *(const bf16x8*)(wq + 512 + kc * 32);
#pragma unroll
      for (int kc = 0; kc < 8; kc++)  wfy[kc] = *(const bf16x8*)(wq + 256 + kc * 32);
    }
  }

  // L1 elementwise ownership (all threads): batch eb, unit ej
  const int eb = tid >> 4, ej = tid & 15;
  const float4 bq = *(const float4*)(bias1p + pbase + ej * 4);
  // L0 elementwise ownership (kh0 lanes): batch-low l0b, unit l0u
  const int l0b = lane >> 2, l0u = lane & 3;
  float c0[2] = {0.f, 0.f};
  float c1 = 0.f;
  unsigned* f0 = bars + bm * 64;
  unsigned* f1 = f0 + 32;
  float* myscr = scr + rw * 640;
  const size_t hoff1 = (size_t)(bbase + eb) * H_ + (bn << 4) + ej;
  const floatx4 zero = {0.f, 0.f, 0.f, 0.f};

  // prologue: h0(-1) = 0 in LDS (hp0 is not read for t=0)
#pragma unroll
  for (int i = 0; i < 4; i++) {
    uint4 z = {0u, 0u, 0u, 0u};
    ((uint4*)h_lds)[tid * 4 + i] = z;
  }
  __syncthreads();

#pragma unroll 1
  for (int t = 0; t <= 64; t++) {
    // ---- Phase B: xg prefetch (kh0), flag1 poll, issue h1(t-2) stage loads
    ushort4 xr0 = {0, 0, 0, 0}, xr1 = {0, 0, 0, 0};
    if (kh == 0 && t < 64) {
      const u16* xp = xg + ((size_t)t * B_ + bbase + l0b) * G_ + pbase + (rw * 4 + l0u) * 4;
      xr0 = *(const ushort4*)xp;
      xr1 = *(const ushort4*)(xp + (size_t)16 * G_);
    }
    if (t >= 1) pollflag(f1, (unsigned)(t - 1), lane, bn);
    u64 w8[8];
    {
      const u64* s1 = (const u64*)(hp1 + (size_t)(t & 1) * (B_ * H_));
#pragma unroll
      for (int i = 0; i < 4; i++) {
        int idx = tid + (i << 9), bb = idx >> 6, u = idx & 63;
        size_t gp = ((size_t)(bbase + bb) * 64 + u) * 2;
        w8[2 * i]     = __hip_atomic_load(s1 + gp,     __ATOMIC_RELAXED, __HIP_MEMORY_SCOPE_AGENT);
        w8[2 * i + 1] = __hip_atomic_load(s1 + gp + 1, __ATOMIC_RELAXED, __HIP_MEMORY_SCOPE_AGENT);
      }
    }

    // ---- Phase C: h0-dependent MFMAs (h1 load latency hides under these)
    floatx4 acc0[2] = {zero, zero};
    floatx4 acc1[2] = {zero, zero};
    if (kh == 0) {
#pragma unroll
      for (int kc = 0; kc < 16; kc++) {
        int sw = ((kc * 4 + qd) ^ (bl & 7)) << 3;
        bf16x8 a0 = *(const bf16x8*)(h_lds + bl * 512 + sw);
        bf16x8 a1 = *(const bf16x8*)(h_lds + (16 + bl) * 512 + sw);
        if (t < 64) {
          acc0[0] = __builtin_amdgcn_mfma_f32_16x16x32_bf16(a0, wfx[kc], acc0[0], 0, 0, 0);
          acc0[1] = __builtin_amdgcn_mfma_f32_16x16x32_bf16(a1, wfx[kc], acc0[1], 0, 0, 0);
        }
        if (kc < 8) {
          acc1[0] = __builtin_amdgcn_mfma_f32_16x16x32_bf16(a0, wfy[kc], acc1[0], 0, 0, 0);
          acc1[1] = __builtin_amdgcn_mfma_f32_16x16x32_bf16(a1, wfy[kc], acc1[1], 0, 0, 0);
        }
      }
    } else {
#pragma unroll
      for (int kc = 0; kc < 8; kc++) {
        int sw = (((8 + kc) * 4 + qd) ^ (bl & 7)) << 3;
        bf16x8 a0 = *(const bf16x8*)(h_lds + bl * 512 + sw);
        bf16x8 a1 = *(const bf16x8*)(h_lds + (16 + bl) * 512 + sw);
        acc1[0] = __builtin_amdgcn_mfma_f32_16x16x32_bf16(a0, wfy[kc], acc1[0], 0, 0, 0);
        acc1[1] = __builtin_amdgcn_mfma_f32_16x16x32_bf16(a1, wfy[kc], acc1[1], 0, 0, 0);
      }
    }
    // write staged h1 to LDS (compiler vmcnt-waits the loads here, after MFMAs)
#pragma unroll
    for (int i = 0; i < 4; i++) {
      int idx = tid + (i << 9), bb = idx >> 6, u = idx & 63;
      int dst = 16384 + bb * 512 + ((u ^ (bb & 7)) << 3);
      uint2 l2 = __builtin_bit_cast(uint2, w8[2 * i]);
      uint2 h2 = __builtin_bit_cast(uint2, w8[2 * i + 1]);
      uint4 q = {l2.x, l2.y, h2.x, h2.y};
      *(uint4*)(h_lds + dst) = q;
    }
    __syncthreads();                               // sync1: h1 ready; h0 reads done

    // ---- Phase D: kh1 pB MFMAs; kh0 L0 transpose+elementwise+h0 store
    if (kh == 1) {
#pragma unroll
      for (int kc = 0; kc < 16; kc++) {
        int sw = ((kc * 4 + qd) ^ (bl & 7)) << 3;
        bf16x8 a0 = *(const bf16x8*)(h_lds + 16384 + bl * 512 + sw);
        bf16x8 a1 = *(const bf16x8*)(h_lds + 16384 + (16 + bl) * 512 + sw);
        acc1[0] = __builtin_amdgcn_mfma_f32_16x16x32_bf16(a0, wfx[kc], acc1[0], 0, 0, 0);
        acc1[1] = __builtin_amdgcn_mfma_f32_16x16x32_bf16(a1, wfx[kc], acc1[1], 0, 0, 0);
      }
    } else if (t < 64) {
      // in-wave transpose of L0 gates (full-K in this wave's acc0)
#pragma unroll
      for (int bt = 0; bt < 2; bt++)
#pragma unroll
        for (int r = 0; r < 4; r++)
          myscr[(bt * 16 + qd * 4 + r) * 20 + bl] = acc0[bt][r];
      asm volatile("s_waitcnt lgkmcnt(0)" ::: "memory");
      __builtin_amdgcn_sched_barrier(0);
#pragma unroll
      for (int bt = 0; bt < 2; bt++) {
        float4 g4 = *(const float4*)(myscr + (bt * 16 + l0b) * 20 + l0u * 4);
        ushort4 xr = bt ? xr1 : xr0;
        float gi = g4.x + bf2f(xr.x);
        float gf = g4.y + bf2f(xr.y);
        float gg = g4.z + bf2f(xr.z);
        float go = g4.w + bf2f(xr.w);
        c0[bt] = sigm(gf) * c0[bt] + sigm(gi) * tanh_(gg);
        float h = sigm(go) * tanh_(c0[bt]);
        __hip_atomic_store(hp0 + (size_t)(t & 1) * (B_ * H_)
                             + (size_t)(bbase + bt * 16 + l0b) * H_
                             + (bn << 4) + rw * 4 + l0u,
                           f2bf(h), __ATOMIC_RELAXED, __HIP_MEMORY_SCOPE_AGENT);
      }
    }
    // L1 partial gates (kh0: pA 0-7; kh1: pA 8-15 + pB)
    {
      const int rowc = rw * 16 + bl;
#pragma unroll
      for (int bt = 0; bt < 2; bt++)
#pragma unroll
        for (int r = 0; r < 4; r++)
          gates1[(kh * 32 + bt * 16 + qd * 4 + r) * 68 + rowc] = acc1[bt][r];
    }
    __syncthreads();                               // sync2: gates1 ready; h0 stores drained

    // ---- Phase E: flag0 publish+poll, h0(t) re-stage (RT hides under L1 elem)
    u64 v8[8];
    if (t < 64) {
      if (tid == 0)
        __hip_atomic_store(f0 + bn, (unsigned)(t + 1),
                           __ATOMIC_RELAXED, __HIP_MEMORY_SCOPE_AGENT);
      pollflag(f0, (unsigned)(t + 1), lane, bn);
      const u64* s0 = (const u64*)(hp0 + (size_t)(t & 1) * (B_ * H_));
#pragma unroll
      for (int i = 0; i < 4; i++) {
        int idx = tid + (i << 9), bb = idx >> 6, u = idx & 63;
        size_t gp = ((size_t)(bbase + bb) * 64 + u) * 2;
        v8[2 * i]     = __hip_atomic_load(s0 + gp,     __ATOMIC_RELAXED, __HIP_MEMORY_SCOPE_AGENT);
        v8[2 * i + 1] = __hip_atomic_load(s0 + gp + 1, __ATOMIC_RELAXED, __HIP_MEMORY_SCOPE_AGENT);
      }
    }
    if (t >= 1) {
      float4 ga = *(const float4*)(gates1 + (0 * 32 + eb) * 68 + ej * 4);
      float4 gc = *(const float4*)(gates1 + (1 * 32 + eb) * 68 + ej * 4);
      float gi = ga.x + gc.x + bq.x;
      float gf = ga.y + gc.y + bq.y;
      float gg = ga.z + gc.z + bq.z;
      float go = ga.w + gc.w + bq.w;
      c1 = sigm(gf) * c1 + sigm(gi) * tanh_(gg);
      float h = sigm(go) * tanh_(c1);
      u16 hb = f2bf(h);
      if (t < 64)
        __hip_atomic_store(hp1 + (size_t)((t + 1) & 1) * (B_ * H_) + hoff1, hb,
                           __ATOMIC_RELAXED, __HIP_MEMORY_SCOPE_AGENT);
      else
        hfin[hoff1] = hb;
    }
    if (t < 64) {
#pragma unroll
      for (int i = 0; i < 4; i++) {
        int idx = tid + (i << 9), bb = idx >> 6, u = idx & 63;
        int dst = bb * 512 + ((u ^ (bb & 7)) << 3);
        uint2 l2 = __builtin_bit_cast(uint2, v8[2 * i]);
        uint2 h2 = __builtin_bit_cast(uint2, v8[2 * i + 1]);
        uint4 q = {l2.x, l2.y, h2.x, h2.y};
        *(uint4*)(h_lds + dst) = q;
      }
    }
    __syncthreads();                               // sync3: h_lds[0] ready; h1 stores drained
    if (t >= 1 && t < 64 && tid == 0)
      __hip_atomic_store(f1 + bn, (unsigned)t,
                         __ATOMIC_RELAXED, __HIP_MEMORY_SCOPE_AGENT);
  }
}

// ---------------------------------------------------------------- Sigma: out[b] = G_b @ Ld_b^T + diag(idio)
__global__ __launch_bounds__(256) void sigma_kernel(
    const u16* __restrict__ Gb, const u16* __restrict__ Ldb,
    const float* __restrict__ idio, float* __restrict__ out)
{
  const int bz = blockIdx.z;
  const int n0 = blockIdx.y * 128;
  const int m0 = blockIdx.x * 128;
  __shared__ alignas(16) u16 As[128 * 32];
  __shared__ alignas(16) u16 Bs[128 * 32];
  const int tid = threadIdx.x, wave = tid >> 6, lane = tid & 63;
  const int wr = wave >> 1, wc = wave & 1;

  const u16* ga = Gb  + (size_t)bz * (512 * 32) + n0 * 32;
  const u16* gb = Ldb + (size_t)bz * (512 * 32) + m0 * 32;
#pragma unroll
  for (int i = 0; i < 2; i++) {
    int idx = tid + (i << 8);
    int row = idx >> 2, ks = idx & 3;
    int off = row * 32 + ((ks ^ (row & 3)) << 3);
    *(uint4*)(As + off) = *(const uint4*)(ga + idx * 8);
    *(uint4*)(Bs + off) = *(const uint4*)(gb + idx * 8);
  }
  __syncthreads();

  const int kg = lane >> 4;
  bf16x8 af[4], bfr[4];
#pragma unroll
  for (int i = 0; i < 4; i++) {
    int rowa = wr * 64 + i * 16 + (lane & 15);
    af[i] = *(const bf16x8*)(As + rowa * 32 + ((kg ^ (rowa & 3)) << 3));
    int rowb = wc * 64 + i * 16 + (lane & 15);
    bfr[i] = *(const bf16x8*)(Bs + rowb * 32 + ((kg ^ (rowb & 3)) << 3));
  }
  floatx4 zero = {0.f, 0.f, 0.f, 0.f};
  floatx4 acc[4][4];
#pragma unroll
  for (int i = 0; i < 4; i++)
#pragma unroll
    for (int j = 0; j < 4; j++)
      acc[i][j] = __builtin_amdgcn_mfma_f32_16x16x32_bf16(af[i], bfr[j], zero, 0, 0, 0);

  const int r0 = (lane >> 4) * 4, cl = lane & 15;
  float* ob = out + (size_t)bz * 250000;
#pragma unroll
  for (int j = 0; j < 4; j++) {
    int col = m0 + wc * 64 + j * 16 + cl;
#pragma unroll
    for (int i = 0; i < 4; i++) {
      int row = n0 + wr * 64 + i * 16 + r0;
#pragma unroll
      for (int r = 0; r < 4; r++) {
        int rr = row + r;
        if (rr < 500 && col < 500) {
          float v = acc[i][j][r];
          if (rr == col) v += idio[(size_t)bz * 500 + rr];
          ob[(size_t)rr * 500 + col] = v;
        }
      }
    }
  }
}

// ---------------------------------------------------------------- launcher
extern "C" void kernel_launch(void* const* d_in, const int* in_sizes, int n_in,
                              void* d_out, int out_size, void* d_ws, size_t ws_size,
                              hipStream_t stream)
{
  const float* x     = (const float*)d_in[0];
  const float* w_ih0 = (const float*)d_in[1];
  const float* w_hh0 = (const float*)d_in[2];
  const float* b_ih0 = (const float*)d_in[3];
  const float* b_hh0 = (const float*)d_in[4];
  const float* w_ih1 = (const float*)d_in[5];
  const float* w_hh1 = (const float*)d_in[6];
  const float* b_ih1 = (const float*)d_in[7];
  const float* b_hh1 = (const float*)d_in[8];
  const float* fc_w  = (const float*)d_in[9];
  const float* fc_b  = (const float*)d_in[10];
  float* out = (float*)d_out;

  char* p = (char*)d_ws;
  auto alloc = [&](size_t n) { char* r = p; p += (n + 255) & ~(size_t)255; return r; };

  u16*  xb     = (u16*)alloc((size_t)T_ * B_ * 512 * 2);
  u16*  wih0b  = (u16*)alloc((size_t)2048 * 512 * 2);
  u16*  whh0b  = (u16*)alloc((size_t)2048 * 512 * 2);
  u16*  w1b    = (u16*)alloc((size_t)2048 * 1024 * 2);
  u16*  fcwb   = (u16*)alloc((size_t)NDP * 512 * 2);
  float* bias0p = (float*)alloc(2048 * 4);
  float* bias1p = (float*)alloc(2048 * 4);
  float* fcbp   = (float*)alloc((size_t)NDP * 4);
  u16*  xg0    = (u16*)alloc((size_t)T_ * B_ * G_ * 2);
  u16*  hp0    = (u16*)alloc((size_t)2 * B_ * H_ * 2);
  u16*  hp1    = (u16*)alloc((size_t)2 * B_ * H_ * 2);
  u16*  hfin   = (u16*)alloc((size_t)B_ * H_ * 2);
  float* raw    = (float*)alloc((size_t)B_ * NDP * 4);
  u16*  Gbuf   = (u16*)alloc((size_t)256 * 512 * 32 * 2);
  u16*  Ldbuf  = (u16*)alloc((size_t)256 * 512 * 32 * 2);
  float* idio   = (float*)alloc((size_t)256 * 512 * 4);
  unsigned* bars0 = (unsigned*)alloc(8 * 64 * 4);

  hipMemsetAsync(hp0, 0, (size_t)2 * B_ * H_ * 2, stream);
  hipMemsetAsync(hp1, 0, (size_t)2 * B_ * H_ * 2, stream);
  hipMemsetAsync(bars0, 0, 8 * 64 * 4, stream);

  dim3 blk(256);
  prep_weights_kernel<<<512, blk, 0, stream>>>(w_ih0, w_hh0, b_ih0, b_hh0,
                                               w_ih1, w_hh1, b_ih1, b_hh1,
                                               fc_w, fc_b,
                                               wih0b, whh0b, w1b, fcwb,
                                               bias0p, bias1p, fcbp);
  prep_x_kernel<<<1024, blk, 0, stream>>>(x, xb);

  // xg0 = xb @ wih0b^T + (b_ih0 + b_hh0)   [16384 x 2048 x 512]
  gemm_bt<1><<<dim3(G_ / 128, (T_ * B_) / 128), blk, 0, stream>>>(
      xb, wih0b, bias0p, xg0, T_ * B_, G_, 512);

  // fused two-layer LSTM; final h1(63) lands in hfin
  lstm_fused_kernel<<<256, dim3(512), 0, stream>>>(
      xg0, whh0b, w1b, bias1p, hp0, hp1, hfin, bars0);

  // raw = h1_final @ fcwb^T + fc_b  [256 x 16640 x 512]
  gemm_bt<0><<<dim3(NDP / 128, B_ / 128), blk, 0, stream>>>(
      hfin, fcwb, fcbp, raw, B_, NDP, 512);

  prep_sigma_kernel<<<1024, blk, 0, stream>>>(raw, Gbuf, Ldbuf, idio);
  sigma_kernel<<<dim3(4, 4, 256), blk, 0, stream>>>(Gbuf, Ldbuf, idio, out);
}